// Round 15
// baseline (507.124 us; speedup 1.0000x reference)
//
#include <hip/hip_runtime.h>
#include <math.h>

#define N_NODES 50000
#define IN_DIM  1000
#define HIDDEN  256
#define N_EDGES 1600000
#define NBLK    196      // ceil(50000/256)
#define NSTEP   63       // ceil(1000/16)

typedef short bf16x8 __attribute__((ext_vector_type(8)));
typedef float f32x16 __attribute__((ext_vector_type(16)));

__device__ __forceinline__ unsigned short f2bf_rne(float f) {
    unsigned u = __builtin_bit_cast(unsigned, f);
    unsigned r = (u + 0x7FFFu + ((u >> 16) & 1u)) >> 16;
    return (unsigned short)r;
}
__device__ __forceinline__ float bf2f(unsigned short b) {
    unsigned u = ((unsigned)b) << 16;
    return __builtin_bit_cast(float, u);
}
__device__ __forceinline__ unsigned cvt_pk_bf16(float a, float b) {
    unsigned r;
    asm("v_cvt_pk_bf16_f32 %0, %1, %2" : "=v"(r) : "v"(a), "v"(b));
    return r;   // [15:0]=bf16(a), [31:16]=bf16(b)
}

// ---------------- degree histogram ----------------
__global__ void hist_kernel(const int* __restrict__ ei, int* __restrict__ cnt) {
    int e = blockIdx.x * blockDim.x + threadIdx.x;
    int stride = gridDim.x * blockDim.x;
    for (; e < N_EDGES; e += stride) {
        int d = ei[N_EDGES + e];
        if ((unsigned)d < N_NODES) atomicAdd(&cnt[d], 1);
    }
}

// ---------------- 3-phase scan ----------------
__global__ __launch_bounds__(256) void scan_sums(const int* __restrict__ cnt, int* __restrict__ bsum) {
    __shared__ int s[256];
    int t = threadIdx.x;
    int i = blockIdx.x * 256 + t;
    s[t] = (i < N_NODES) ? cnt[i] : 0;
    __syncthreads();
    #pragma unroll
    for (int off = 128; off > 0; off >>= 1) {
        if (t < off) s[t] += s[t + off];
        __syncthreads();
    }
    if (t == 0) bsum[blockIdx.x] = s[0];
}

__global__ __launch_bounds__(256) void scan_top(int* __restrict__ bsum) {
    __shared__ int s[256];
    int t = threadIdx.x;
    int v = (t < NBLK) ? bsum[t] : 0;
    s[t] = v;
    __syncthreads();
    for (int off = 1; off < 256; off <<= 1) {
        int x = (t >= off) ? s[t - off] : 0;
        __syncthreads();
        s[t] += x;
        __syncthreads();
    }
    if (t < NBLK) bsum[t] = s[t] - v;   // exclusive
}

__global__ __launch_bounds__(256) void scan_write(const int* __restrict__ cnt, const int* __restrict__ bsum,
                                                  int* __restrict__ rowoff, int* __restrict__ cursor,
                                                  float* __restrict__ dinv) {
    __shared__ int s[256];
    int t = threadIdx.x;
    int i = blockIdx.x * 256 + t;
    int v = (i < N_NODES) ? cnt[i] : 0;
    s[t] = v;
    __syncthreads();
    for (int off = 1; off < 256; off <<= 1) {
        int x = (t >= off) ? s[t - off] : 0;
        __syncthreads();
        s[t] += x;
        __syncthreads();
    }
    if (i < N_NODES) {
        int ro = bsum[blockIdx.x] + s[t] - v;   // exclusive
        rowoff[i] = ro;
        cursor[i] = ro;
        dinv[i]  = rsqrtf((float)v + 1.0f);
    }
}

// ---------------- counting-sort scatter ----------------
__global__ void scatter_kernel(const int* __restrict__ ei,
                               int* __restrict__ cursor, int* __restrict__ csr) {
    int e = blockIdx.x * blockDim.x + threadIdx.x;
    int stride = gridDim.x * blockDim.x;
    for (; e < N_EDGES; e += stride) {
        int s = ei[e];
        int d = ei[N_EDGES + e];
        if ((unsigned)d < N_NODES && (unsigned)s < N_NODES) {
            int pos = atomicAdd(&cursor[d], 1);
            csr[pos] = s;
        }
    }
}

// ---------------- W1 split + pack per-step fragment blocks ----------------
// Wp[step 0..63][ci 0..7][pl 0..1][lane][8] (bf16), 1KB chunks; k>=1000 zeroed.
__global__ __launch_bounds__(256) void wsplit_kernel(const float* __restrict__ W1,
                                                     unsigned short* __restrict__ Wp) {
    int idx = blockIdx.x * 256 + threadIdx.x;   // 256 cols * 1024 k
    int c = idx >> 10, k = idx & 1023;
    float v = (k < IN_DIM) ? W1[(size_t)k * HIDDEN + c] : 0.0f;
    unsigned short hb = f2bf_rne(v);
    unsigned short lb = f2bf_rne(v - bf2f(hb));
    int ci = c >> 5;
    int step = k >> 4, kk = k & 15;
    int lane = (kk >> 3) * 32 + (c & 31);
    int j = kk & 7;
    size_t base = ((size_t)((step * 8 + ci) * 2) * 64 + lane) * 8 + j;
    Wp[base] = hb;          // plane h
    Wp[base + 512] = lb;    // plane l
}

// ---------------- GEMM1: single-wave blocks, ZERO LDS, ZERO barriers ----------------
// 6252 blocks x 64 thr (1 wave). Wave: 32 rows x 64 cols. B: global->VGPR
// coalesced 1KB reads from packed Wp (co-resident waves share L1). A: per-lane
// row gather (X L3-resident on re-reads). Both prefetched 1 step ahead in regs.
// 16-20 independent wave-streams/CU, no sync points at all.
__global__ __launch_bounds__(64, 4) void gemm1_mfma(const float* __restrict__ X,
                                                    const unsigned short* __restrict__ Wp,
                                                    const float* __restrict__ dinv,
                                                    unsigned short* __restrict__ G1b) {
    const int l  = threadIdx.x;
    const int lr = l & 31;
    const int lq = l >> 5;
    const int mb = blockIdx.x >> 2;
    const int cg = blockIdx.x & 3;       // col-group: cols cg*64..+63 (slabs cg*2, cg*2+1)
    const int m0 = mb * 32;

    int arow = m0 + lr;
    const float* ap = X + (size_t)(arow < N_NODES ? arow : N_NODES - 1) * IN_DIM + lq * 8;
    const unsigned short* bp = Wp + (size_t)cg * 2048 + l * 8;   // step stride 8192 shorts

    f32x16 acc[2] = {};

    // prefetch step 0 (k = lq*8..+7 <= 15, always valid)
    float4 a0 = *(const float4*)ap;
    float4 a1 = *(const float4*)(ap + 4);
    bf16x8 b0h = *(const bf16x8*)(bp);
    bf16x8 b0l = *(const bf16x8*)(bp + 512);
    bf16x8 b1h = *(const bf16x8*)(bp + 1024);
    bf16x8 b1l = *(const bf16x8*)(bp + 1536);

    #pragma unroll 2
    for (int s = 0; s < NSTEP; ++s) {
        // issue prefetch for s+1 (consumed next iteration; compiler pipelines)
        float4 na0 = make_float4(0.f, 0.f, 0.f, 0.f), na1 = na0;
        bf16x8 nb0h = {}, nb0l = {}, nb1h = {}, nb1l = {};
        if (s + 1 < NSTEP) {
            const unsigned short* nbp = bp + (size_t)(s + 1) * 8192;
            nb0h = *(const bf16x8*)(nbp);
            nb0l = *(const bf16x8*)(nbp + 512);
            nb1h = *(const bf16x8*)(nbp + 1024);
            nb1l = *(const bf16x8*)(nbp + 1536);
            int kn = (s + 1) * 16 + lq * 8;
            if (kn <= IN_DIM - 8) {
                na0 = *(const float4*)(ap + (size_t)(s + 1) * 16);
                na1 = *(const float4*)(ap + (size_t)(s + 1) * 16 + 4);
            }
        }
        // cvt current A to bf16 fragment
        unsigned h0 = cvt_pk_bf16(a0.x, a0.y);
        unsigned h1 = cvt_pk_bf16(a0.z, a0.w);
        unsigned h2 = cvt_pk_bf16(a1.x, a1.y);
        unsigned h3 = cvt_pk_bf16(a1.z, a1.w);
        uint4 au = make_uint4(h0, h1, h2, h3);
        bf16x8 a = __builtin_bit_cast(bf16x8, au);

        // same accumulator order as rounds 8-14 (bit-identical result)
        acc[0] = __builtin_amdgcn_mfma_f32_32x32x16_bf16(a, b0h, acc[0], 0, 0, 0);
        acc[0] = __builtin_amdgcn_mfma_f32_32x32x16_bf16(a, b0l, acc[0], 0, 0, 0);
        acc[1] = __builtin_amdgcn_mfma_f32_32x32x16_bf16(a, b1h, acc[1], 0, 0, 0);
        acc[1] = __builtin_amdgcn_mfma_f32_32x32x16_bf16(a, b1l, acc[1], 0, 0, 0);

        a0 = na0; a1 = na1;
        b0h = nb0h; b0l = nb0l; b1h = nb1h; b1l = nb1l;
    }

    // epilogue -> slab-major: G1b[(slab*N + row)*32 + lr], slab = cg*2 + ni
    #pragma unroll
    for (int r = 0; r < 16; ++r) {
        int row = m0 + (r & 3) + 8 * (r >> 2) + 4 * lq;
        if (row >= N_NODES) continue;
        float dv = dinv[row];
        #pragma unroll
        for (int ni = 0; ni < 2; ++ni) {
            int slab = cg * 2 + ni;
            G1b[((size_t)slab * N_NODES + row) * 32 + lr] = f2bf_rne(dv * acc[ni][r]);
        }
    }
}

// ---------------- slab-partitioned agg1 + partial gemm2 (slab-major g1b) ----------------
__global__ __launch_bounds__(256) void aggslab_kernel(const unsigned short* __restrict__ G,
                                                      const int* __restrict__ csr,
                                                      const int* __restrict__ rowoff,
                                                      const int* __restrict__ cnt,
                                                      const float* __restrict__ dinv,
                                                      const float* __restrict__ b1,
                                                      const float* __restrict__ W2,
                                                      float* __restrict__ part) {
    const int tid  = threadIdx.x;
    const int slab = blockIdx.x & 7;
    const int nb   = blockIdx.x >> 3;
    const int wave = tid >> 6, lane = tid & 63;
    const int g    = lane >> 3, sl = lane & 7;
    const int d    = nb * 32 + wave * 8 + g;
    if (d >= N_NODES) return;
    const unsigned short* Gs = G + (size_t)slab * N_NODES * 32;
    const int co = sl * 4;
    const int c0 = slab * 32 + co;

    ushort4 sv = *(const ushort4*)&Gs[(size_t)d * 32 + co];
    float ax = bf2f(sv.x), ay = bf2f(sv.y), az = bf2f(sv.z), aw = bf2f(sv.w);
    int beg = rowoff[d], num = cnt[d];
    int end = beg + num;
    int e = beg;
    for (; e + 4 <= end; e += 4) {
        int s0 = csr[e], s1 = csr[e + 1], s2 = csr[e + 2], s3 = csr[e + 3];
        ushort4 v0 = *(const ushort4*)&Gs[(size_t)s0 * 32 + co];
        ushort4 v1 = *(const ushort4*)&Gs[(size_t)s1 * 32 + co];
        ushort4 v2 = *(const ushort4*)&Gs[(size_t)s2 * 32 + co];
        ushort4 v3 = *(const ushort4*)&Gs[(size_t)s3 * 32 + co];
        ax += bf2f(v0.x); ay += bf2f(v0.y); az += bf2f(v0.z); aw += bf2f(v0.w);
        ax += bf2f(v1.x); ay += bf2f(v1.y); az += bf2f(v1.z); aw += bf2f(v1.w);
        ax += bf2f(v2.x); ay += bf2f(v2.y); az += bf2f(v2.z); aw += bf2f(v2.w);
        ax += bf2f(v3.x); ay += bf2f(v3.y); az += bf2f(v3.z); aw += bf2f(v3.w);
    }
    for (; e < end; ++e) {
        int s = csr[e];
        ushort4 v = *(const ushort4*)&Gs[(size_t)s * 32 + co];
        ax += bf2f(v.x); ay += bf2f(v.y); az += bf2f(v.z); aw += bf2f(v.w);
    }
    float dv = dinv[d];
    float4 bb = *(const float4*)&b1[c0];
    float zx = fmaxf(dv * ax + bb.x, 0.f);
    float zy = fmaxf(dv * ay + bb.y, 0.f);
    float zz = fmaxf(dv * az + bb.z, 0.f);
    float zw = fmaxf(dv * aw + bb.w, 0.f);
    float2 w0 = *(const float2*)&W2[(c0 + 0) * 2];
    float2 w1 = *(const float2*)&W2[(c0 + 1) * 2];
    float2 w2_ = *(const float2*)&W2[(c0 + 2) * 2];
    float2 w3 = *(const float2*)&W2[(c0 + 3) * 2];
    float p0 = zx * w0.x + zy * w1.x + zz * w2_.x + zw * w3.x;
    float p1 = zx * w0.y + zy * w1.y + zz * w2_.y + zw * w3.y;
    #pragma unroll
    for (int off = 1; off < 8; off <<= 1) {
        p0 += __shfl_xor(p0, off, 64);
        p1 += __shfl_xor(p1, off, 64);
    }
    if (sl == 0)
        *(float2*)&part[((size_t)slab * N_NODES + d) * 2] = make_float2(p0, p1);
}

// ---------------- g2 = dinv * sum_slab(part) ----------------
__global__ __launch_bounds__(256) void g2reduce_kernel(const float* __restrict__ part,
                                                       const float* __restrict__ dinv,
                                                       float* __restrict__ G2) {
    int i = blockIdx.x * 256 + threadIdx.x;
    if (i >= N_NODES) return;
    float a0 = 0.f, a1 = 0.f;
    #pragma unroll
    for (int s = 0; s < 8; ++s) {
        float2 p = *(const float2*)&part[((size_t)s * N_NODES + i) * 2];
        a0 += p.x; a1 += p.y;
    }
    float dv = dinv[i];
    G2[i * 2 + 0] = dv * a0;
    G2[i * 2 + 1] = dv * a1;
}

// ---------------- agg2 ----------------
__global__ __launch_bounds__(256) void agg2_kernel(const float* __restrict__ G2,
                                                   const int* __restrict__ csr,
                                                   const int* __restrict__ rowoff,
                                                   const int* __restrict__ cnt,
                                                   const float* __restrict__ dinv,
                                                   const float* __restrict__ b2,
                                                   float* __restrict__ out) {
    int wave = threadIdx.x >> 6, lane = threadIdx.x & 63;
    int d = blockIdx.x * 4 + wave;
    if (d >= N_NODES) return;
    int beg = rowoff[d], num = cnt[d];
    float a0 = 0.f, a1 = 0.f;
    for (int e = lane; e < num; e += 64) {
        int s = csr[beg + e];
        float2 g = *(const float2*)&G2[s * 2];
        a0 += g.x; a1 += g.y;
    }
    #pragma unroll
    for (int off = 32; off; off >>= 1) {
        a0 += __shfl_xor(a0, off, 64);
        a1 += __shfl_xor(a1, off, 64);
    }
    if (lane == 0) {
        float2 self = *(const float2*)&G2[d * 2];
        float dv = dinv[d];
        out[d * 2 + 0] = dv * (a0 + self.x) + b2[0];
        out[d * 2 + 1] = dv * (a1 + self.y) + b2[1];
    }
}

// ---------------- workspace layout (bytes) ----------------
#define OFF_CNT     0u
#define OFF_ROWOFF  262144u
#define OFF_CURSOR  524288u
#define OFF_DINV    786432u
#define OFF_BSUM    1048576u
#define OFF_CSR     1310720u
#define OFF_WP      8388608u     // 1 MB packed per-step (h+l)
#define OFF_G1B     9437184u     // 25.6 MB slab-major
#define OFF_G2      35651584u    // 400 KB
#define OFF_PART    36700160u    // 3.2 MB
// total ~40 MB

extern "C" void kernel_launch(void* const* d_in, const int* in_sizes, int n_in,
                              void* d_out, int out_size, void* d_ws, size_t ws_size,
                              hipStream_t stream) {
    const float* x  = (const float*)d_in[0];
    const float* W1 = (const float*)d_in[1];
    const float* b1 = (const float*)d_in[2];
    const float* W2 = (const float*)d_in[3];
    const float* b2 = (const float*)d_in[4];
    const int*   ei = (const int*)d_in[5];

    char* ws = (char*)d_ws;
    int*   cnt    = (int*)  (ws + OFF_CNT);
    int*   rowoff = (int*)  (ws + OFF_ROWOFF);
    int*   cursor = (int*)  (ws + OFF_CURSOR);
    float* dinv   = (float*)(ws + OFF_DINV);
    int*   bsum   = (int*)  (ws + OFF_BSUM);
    int*   csr    = (int*)  (ws + OFF_CSR);
    unsigned short* wp  = (unsigned short*)(ws + OFF_WP);
    unsigned short* g1b = (unsigned short*)(ws + OFF_G1B);
    float* g2     = (float*)(ws + OFF_G2);
    float* part   = (float*)(ws + OFF_PART);
    float* out    = (float*)d_out;

    hipMemsetAsync(cnt, 0, N_NODES * sizeof(int), stream);
    hist_kernel<<<2048, 256, 0, stream>>>(ei, cnt);
    scan_sums<<<NBLK, 256, 0, stream>>>(cnt, bsum);
    scan_top<<<1, 256, 0, stream>>>(bsum);
    scan_write<<<NBLK, 256, 0, stream>>>(cnt, bsum, rowoff, cursor, dinv);
    scatter_kernel<<<2048, 256, 0, stream>>>(ei, cursor, csr);
    wsplit_kernel<<<1024, 256, 0, stream>>>(W1, wp);

    gemm1_mfma<<<((N_NODES + 31) / 32) * 4, 64, 0, stream>>>(x, wp, dinv, g1b);

    aggslab_kernel<<<8 * ((N_NODES + 31) / 32), 256, 0, stream>>>(g1b, csr, rowoff, cnt, dinv, b1, W2, part);
    g2reduce_kernel<<<NBLK, 256, 0, stream>>>(part, dinv, g2);
    agg2_kernel<<<(N_NODES + 3) / 4, 256, 0, stream>>>(g2, csr, rowoff, cnt, dinv, b2, out);
}

// Round 16
// 387.589 us; speedup vs baseline: 1.3084x; 1.3084x over previous
//
#include <hip/hip_runtime.h>
#include <math.h>

#define N_NODES 50000
#define IN_DIM  1000
#define HIDDEN  256
#define N_EDGES 1600000
#define NBLK    196      // ceil(50000/256)
#define NSTEP   63       // ceil(1000/16)

typedef short bf16x8 __attribute__((ext_vector_type(8)));
typedef float f32x16 __attribute__((ext_vector_type(16)));

__device__ __forceinline__ unsigned short f2bf_rne(float f) {
    unsigned u = __builtin_bit_cast(unsigned, f);
    unsigned r = (u + 0x7FFFu + ((u >> 16) & 1u)) >> 16;
    return (unsigned short)r;
}
__device__ __forceinline__ float bf2f(unsigned short b) {
    unsigned u = ((unsigned)b) << 16;
    return __builtin_bit_cast(float, u);
}
__device__ __forceinline__ unsigned cvt_pk_bf16(float a, float b) {
    unsigned r;
    asm("v_cvt_pk_bf16_f32 %0, %1, %2" : "=v"(r) : "v"(a), "v"(b));
    return r;   // [15:0]=bf16(a), [31:16]=bf16(b)
}
#define GLOAD_LDS16(gp, lp) \
    __builtin_amdgcn_global_load_lds((const __attribute__((address_space(1))) unsigned*)(gp), \
                                     (__attribute__((address_space(3))) unsigned*)(lp), 16, 0, 0)

// ---------------- degree histogram ----------------
__global__ void hist_kernel(const int* __restrict__ ei, int* __restrict__ cnt) {
    int e = blockIdx.x * blockDim.x + threadIdx.x;
    int stride = gridDim.x * blockDim.x;
    for (; e < N_EDGES; e += stride) {
        int d = ei[N_EDGES + e];
        if ((unsigned)d < N_NODES) atomicAdd(&cnt[d], 1);
    }
}

// ---------------- 3-phase scan ----------------
__global__ __launch_bounds__(256) void scan_sums(const int* __restrict__ cnt, int* __restrict__ bsum) {
    __shared__ int s[256];
    int t = threadIdx.x;
    int i = blockIdx.x * 256 + t;
    s[t] = (i < N_NODES) ? cnt[i] : 0;
    __syncthreads();
    #pragma unroll
    for (int off = 128; off > 0; off >>= 1) {
        if (t < off) s[t] += s[t + off];
        __syncthreads();
    }
    if (t == 0) bsum[blockIdx.x] = s[0];
}

__global__ __launch_bounds__(256) void scan_top(int* __restrict__ bsum) {
    __shared__ int s[256];
    int t = threadIdx.x;
    int v = (t < NBLK) ? bsum[t] : 0;
    s[t] = v;
    __syncthreads();
    for (int off = 1; off < 256; off <<= 1) {
        int x = (t >= off) ? s[t - off] : 0;
        __syncthreads();
        s[t] += x;
        __syncthreads();
    }
    if (t < NBLK) bsum[t] = s[t] - v;   // exclusive
}

__global__ __launch_bounds__(256) void scan_write(const int* __restrict__ cnt, const int* __restrict__ bsum,
                                                  int* __restrict__ rowoff, int* __restrict__ cursor,
                                                  float* __restrict__ dinv) {
    __shared__ int s[256];
    int t = threadIdx.x;
    int i = blockIdx.x * 256 + t;
    int v = (i < N_NODES) ? cnt[i] : 0;
    s[t] = v;
    __syncthreads();
    for (int off = 1; off < 256; off <<= 1) {
        int x = (t >= off) ? s[t - off] : 0;
        __syncthreads();
        s[t] += x;
        __syncthreads();
    }
    if (i < N_NODES) {
        int ro = bsum[blockIdx.x] + s[t] - v;   // exclusive
        rowoff[i] = ro;
        cursor[i] = ro;
        dinv[i]  = rsqrtf((float)v + 1.0f);
    }
}

// ---------------- counting-sort scatter ----------------
__global__ void scatter_kernel(const int* __restrict__ ei,
                               int* __restrict__ cursor, int* __restrict__ csr) {
    int e = blockIdx.x * blockDim.x + threadIdx.x;
    int stride = gridDim.x * blockDim.x;
    for (; e < N_EDGES; e += stride) {
        int s = ei[e];
        int d = ei[N_EDGES + e];
        if ((unsigned)d < N_NODES && (unsigned)s < N_NODES) {
            int pos = atomicAdd(&cursor[d], 1);
            csr[pos] = s;
        }
    }
}

// ---------------- W1 pack, SINGLE bf16 plane ----------------
// Wp[step 0..63][ci 0..7][lane 0..63][j 0..7] (bf16), 512KB total; k>=1000 zeroed.
__global__ __launch_bounds__(256) void wsplit_kernel(const float* __restrict__ W1,
                                                     unsigned short* __restrict__ Wp) {
    int idx = blockIdx.x * 256 + threadIdx.x;   // 256 cols * 1024 k
    int c = idx >> 10, k = idx & 1023;
    float v = (k < IN_DIM) ? W1[(size_t)k * HIDDEN + c] : 0.0f;
    int ci = c >> 5;
    int step = k >> 4, kk = k & 15;
    int lane = (kk >> 3) * 32 + (c & 31);
    int j = kk & 7;
    Wp[((size_t)(step * 8 + ci) * 64 + lane) * 8 + j] = f2bf_rne(v);
}

// ---------------- GEMM1: 64x256, 4 waves, single-plane W (4 MFMA/wave/step) ----------------
// LDS 20KB total -> more resident blocks; B stage halved to 8KB/step.
__global__ __launch_bounds__(256, 4) void gemm1_mfma(const float* __restrict__ X,
                                                     const unsigned short* __restrict__ Wp,
                                                     const float* __restrict__ dinv,
                                                     unsigned short* __restrict__ G1b) {
    __shared__ unsigned short sA[2][1024];   // [mt 2][lane 64][8] bf16 = 2KB/buf
    __shared__ unsigned short sB[2][4096];   // [ci 8][lane 64][8]  bf16 = 8KB/buf
    const int tid = threadIdx.x;
    const int w   = tid >> 6;
    const int l   = tid & 63;
    const int lr  = l & 31;
    const int lq  = l >> 5;
    const int R   = w >> 1;
    const int C   = w & 1;
    const int m0  = blockIdx.x * 64;

    const int rl = tid >> 2;
    const int ss = tid & 3;
    const int smt   = rl >> 5;
    const int slane = (ss >> 1) * 32 + (rl & 31);
    const int sidx  = smt * 512 + slane * 8 + (ss & 1) * 4;   // shorts
    int rg = m0 + rl;
    const float* ap = X + (size_t)(rg < N_NODES ? rg : N_NODES - 1) * IN_DIM + ss * 4;
    const bool svalid_tail = (ss < 2);

    // B staging: wave w stages ci = w*2, w*2+1 (1KB each)
    const unsigned short* bsrc = Wp + (size_t)(w * 2) * 512 + l * 8;

    f32x16 acc[4] = {};

    auto stageB = [&](int s, int buf) {
        const unsigned short* src = bsrc + (size_t)s * 4096;
        GLOAD_LDS16(src,       &sB[buf][(w * 2 + 0) * 512]);
        GLOAD_LDS16(src + 512, &sB[buf][(w * 2 + 1) * 512]);
    };
    auto cvtWriteA = [&](float4 f, int buf) {
        unsigned h0 = cvt_pk_bf16(f.x, f.y);
        unsigned h1 = cvt_pk_bf16(f.z, f.w);
        *(uint2*)&sA[buf][sidx] = make_uint2(h0, h1);
    };

    stageB(0, 0);
    cvtWriteA(*(const float4*)ap, 0);
    float4 rA = *(const float4*)(ap + 16);
    __syncthreads();

    #pragma unroll 1
    for (int s = 0; s < NSTEP; ++s) {
        const int buf = s & 1;
        if (s + 1 < NSTEP) stageB(s + 1, buf ^ 1);
        float4 rN = make_float4(0.f, 0.f, 0.f, 0.f);
        if (s + 2 < NSTEP && (s + 2 < NSTEP - 1 || svalid_tail))
            rN = *(const float4*)(ap + (size_t)(s + 2) * 16);
        if (s + 1 < NSTEP) cvtWriteA(rA, buf ^ 1);

        bf16x8 ah = *(const bf16x8*)&sA[buf][R * 512 + l * 8];
        bf16x8 b[4];
        #pragma unroll
        for (int ni = 0; ni < 4; ++ni)
            b[ni] = *(const bf16x8*)&sB[buf][(C * 4 + ni) * 512 + l * 8];
        #pragma unroll
        for (int ni = 0; ni < 4; ++ni)
            acc[ni] = __builtin_amdgcn_mfma_f32_32x32x16_bf16(ah, b[ni], acc[ni], 0, 0, 0);
        rA = rN;
        __syncthreads();
    }

    // epilogue -> slab-major: G1b[(slab*N + row)*32 + lr], slab = C*4+ni
    #pragma unroll
    for (int r = 0; r < 16; ++r) {
        int row = m0 + R * 32 + (r & 3) + 8 * (r >> 2) + 4 * lq;
        if (row >= N_NODES) continue;
        float dv = dinv[row];
        #pragma unroll
        for (int ni = 0; ni < 4; ++ni) {
            int slab = C * 4 + ni;
            G1b[((size_t)slab * N_NODES + row) * 32 + lr] = f2bf_rne(dv * acc[ni][r]);
        }
    }
}

// ---------------- slab-partitioned agg1 + partial gemm2 (slab-major g1b) ----------------
__global__ __launch_bounds__(256) void aggslab_kernel(const unsigned short* __restrict__ G,
                                                      const int* __restrict__ csr,
                                                      const int* __restrict__ rowoff,
                                                      const int* __restrict__ cnt,
                                                      const float* __restrict__ dinv,
                                                      const float* __restrict__ b1,
                                                      const float* __restrict__ W2,
                                                      float* __restrict__ part) {
    const int tid  = threadIdx.x;
    const int slab = blockIdx.x & 7;
    const int nb   = blockIdx.x >> 3;
    const int wave = tid >> 6, lane = tid & 63;
    const int g    = lane >> 3, sl = lane & 7;
    const int d    = nb * 32 + wave * 8 + g;
    if (d >= N_NODES) return;
    const unsigned short* Gs = G + (size_t)slab * N_NODES * 32;
    const int co = sl * 4;
    const int c0 = slab * 32 + co;

    ushort4 sv = *(const ushort4*)&Gs[(size_t)d * 32 + co];
    float ax = bf2f(sv.x), ay = bf2f(sv.y), az = bf2f(sv.z), aw = bf2f(sv.w);
    int beg = rowoff[d], num = cnt[d];
    int end = beg + num;
    int e = beg;
    // 8-deep MLP (CSR order preserved)
    for (; e + 8 <= end; e += 8) {
        int s0 = csr[e], s1 = csr[e+1], s2 = csr[e+2], s3 = csr[e+3];
        int s4 = csr[e+4], s5 = csr[e+5], s6 = csr[e+6], s7 = csr[e+7];
        ushort4 v0 = *(const ushort4*)&Gs[(size_t)s0 * 32 + co];
        ushort4 v1 = *(const ushort4*)&Gs[(size_t)s1 * 32 + co];
        ushort4 v2 = *(const ushort4*)&Gs[(size_t)s2 * 32 + co];
        ushort4 v3 = *(const ushort4*)&Gs[(size_t)s3 * 32 + co];
        ushort4 v4 = *(const ushort4*)&Gs[(size_t)s4 * 32 + co];
        ushort4 v5 = *(const ushort4*)&Gs[(size_t)s5 * 32 + co];
        ushort4 v6 = *(const ushort4*)&Gs[(size_t)s6 * 32 + co];
        ushort4 v7 = *(const ushort4*)&Gs[(size_t)s7 * 32 + co];
        ax += bf2f(v0.x); ay += bf2f(v0.y); az += bf2f(v0.z); aw += bf2f(v0.w);
        ax += bf2f(v1.x); ay += bf2f(v1.y); az += bf2f(v1.z); aw += bf2f(v1.w);
        ax += bf2f(v2.x); ay += bf2f(v2.y); az += bf2f(v2.z); aw += bf2f(v2.w);
        ax += bf2f(v3.x); ay += bf2f(v3.y); az += bf2f(v3.z); aw += bf2f(v3.w);
        ax += bf2f(v4.x); ay += bf2f(v4.y); az += bf2f(v4.z); aw += bf2f(v4.w);
        ax += bf2f(v5.x); ay += bf2f(v5.y); az += bf2f(v5.z); aw += bf2f(v5.w);
        ax += bf2f(v6.x); ay += bf2f(v6.y); az += bf2f(v6.z); aw += bf2f(v6.w);
        ax += bf2f(v7.x); ay += bf2f(v7.y); az += bf2f(v7.z); aw += bf2f(v7.w);
    }
    for (; e < end; ++e) {
        int s = csr[e];
        ushort4 v = *(const ushort4*)&Gs[(size_t)s * 32 + co];
        ax += bf2f(v.x); ay += bf2f(v.y); az += bf2f(v.z); aw += bf2f(v.w);
    }
    float dv = dinv[d];
    float4 bb = *(const float4*)&b1[c0];
    float zx = fmaxf(dv * ax + bb.x, 0.f);
    float zy = fmaxf(dv * ay + bb.y, 0.f);
    float zz = fmaxf(dv * az + bb.z, 0.f);
    float zw = fmaxf(dv * aw + bb.w, 0.f);
    float2 w0 = *(const float2*)&W2[(c0 + 0) * 2];
    float2 w1 = *(const float2*)&W2[(c0 + 1) * 2];
    float2 w2_ = *(const float2*)&W2[(c0 + 2) * 2];
    float2 w3 = *(const float2*)&W2[(c0 + 3) * 2];
    float p0 = zx * w0.x + zy * w1.x + zz * w2_.x + zw * w3.x;
    float p1 = zx * w0.y + zy * w1.y + zz * w2_.y + zw * w3.y;
    #pragma unroll
    for (int off = 1; off < 8; off <<= 1) {
        p0 += __shfl_xor(p0, off, 64);
        p1 += __shfl_xor(p1, off, 64);
    }
    if (sl == 0)
        *(float2*)&part[((size_t)slab * N_NODES + d) * 2] = make_float2(p0, p1);
}

// ---------------- g2 = dinv * sum_slab(part) ----------------
__global__ __launch_bounds__(256) void g2reduce_kernel(const float* __restrict__ part,
                                                       const float* __restrict__ dinv,
                                                       float* __restrict__ G2) {
    int i = blockIdx.x * 256 + threadIdx.x;
    if (i >= N_NODES) return;
    float a0 = 0.f, a1 = 0.f;
    #pragma unroll
    for (int s = 0; s < 8; ++s) {
        float2 p = *(const float2*)&part[((size_t)s * N_NODES + i) * 2];
        a0 += p.x; a1 += p.y;
    }
    float dv = dinv[i];
    G2[i * 2 + 0] = dv * a0;
    G2[i * 2 + 1] = dv * a1;
}

// ---------------- agg2 ----------------
__global__ __launch_bounds__(256) void agg2_kernel(const float* __restrict__ G2,
                                                   const int* __restrict__ csr,
                                                   const int* __restrict__ rowoff,
                                                   const int* __restrict__ cnt,
                                                   const float* __restrict__ dinv,
                                                   const float* __restrict__ b2,
                                                   float* __restrict__ out) {
    int wave = threadIdx.x >> 6, lane = threadIdx.x & 63;
    int d = blockIdx.x * 4 + wave;
    if (d >= N_NODES) return;
    int beg = rowoff[d], num = cnt[d];
    float a0 = 0.f, a1 = 0.f;
    for (int e = lane; e < num; e += 64) {
        int s = csr[beg + e];
        float2 g = *(const float2*)&G2[s * 2];
        a0 += g.x; a1 += g.y;
    }
    #pragma unroll
    for (int off = 32; off; off >>= 1) {
        a0 += __shfl_xor(a0, off, 64);
        a1 += __shfl_xor(a1, off, 64);
    }
    if (lane == 0) {
        float2 self = *(const float2*)&G2[d * 2];
        float dv = dinv[d];
        out[d * 2 + 0] = dv * (a0 + self.x) + b2[0];
        out[d * 2 + 1] = dv * (a1 + self.y) + b2[1];
    }
}

// ---------------- workspace layout (bytes) ----------------
#define OFF_CNT     0u
#define OFF_ROWOFF  262144u
#define OFF_CURSOR  524288u
#define OFF_DINV    786432u
#define OFF_BSUM    1048576u
#define OFF_CSR     1310720u
#define OFF_WP      8388608u     // 512 KB packed single-plane
#define OFF_G1B     9437184u     // 25.6 MB slab-major
#define OFF_G2      35651584u    // 400 KB
#define OFF_PART    36700160u    // 3.2 MB
// total ~40 MB

extern "C" void kernel_launch(void* const* d_in, const int* in_sizes, int n_in,
                              void* d_out, int out_size, void* d_ws, size_t ws_size,
                              hipStream_t stream) {
    const float* x  = (const float*)d_in[0];
    const float* W1 = (const float*)d_in[1];
    const float* b1 = (const float*)d_in[2];
    const float* W2 = (const float*)d_in[3];
    const float* b2 = (const float*)d_in[4];
    const int*   ei = (const int*)d_in[5];

    char* ws = (char*)d_ws;
    int*   cnt    = (int*)  (ws + OFF_CNT);
    int*   rowoff = (int*)  (ws + OFF_ROWOFF);
    int*   cursor = (int*)  (ws + OFF_CURSOR);
    float* dinv   = (float*)(ws + OFF_DINV);
    int*   bsum   = (int*)  (ws + OFF_BSUM);
    int*   csr    = (int*)  (ws + OFF_CSR);
    unsigned short* wp  = (unsigned short*)(ws + OFF_WP);
    unsigned short* g1b = (unsigned short*)(ws + OFF_G1B);
    float* g2     = (float*)(ws + OFF_G2);
    float* part   = (float*)(ws + OFF_PART);
    float* out    = (float*)d_out;

    hipMemsetAsync(cnt, 0, N_NODES * sizeof(int), stream);
    hist_kernel<<<2048, 256, 0, stream>>>(ei, cnt);
    scan_sums<<<NBLK, 256, 0, stream>>>(cnt, bsum);
    scan_top<<<1, 256, 0, stream>>>(bsum);
    scan_write<<<NBLK, 256, 0, stream>>>(cnt, bsum, rowoff, cursor, dinv);
    scatter_kernel<<<2048, 256, 0, stream>>>(ei, cursor, csr);
    wsplit_kernel<<<1024, 256, 0, stream>>>(W1, wp);

    gemm1_mfma<<<(N_NODES + 63) / 64, 256, 0, stream>>>(x, wp, dinv, g1b);

    aggslab_kernel<<<8 * ((N_NODES + 31) / 32), 256, 0, stream>>>(g1b, csr, rowoff, cnt, dinv, b1, W2, part);
    g2reduce_kernel<<<NBLK, 256, 0, stream>>>(part, dinv, g2);
    agg2_kernel<<<(N_NODES + 3) / 4, 256, 0, stream>>>(g2, csr, rowoff, cnt, dinv, b2, out);
}

// Round 17
// 297.328 us; speedup vs baseline: 1.7056x; 1.3036x over previous
//
#include <hip/hip_runtime.h>
#include <math.h>

#define N_NODES 50000
#define IN_DIM  1000
#define HIDDEN  256
#define N_EDGES 1600000
#define NBLK    196      // ceil(50000/256)
#define NSTEP   63       // ceil(1000/16)
#define GEMM_BLOCKS ((N_NODES + 63) / 64)   // 782
#define SCAT_BLOCKS 512

typedef short bf16x8 __attribute__((ext_vector_type(8)));
typedef float f32x16 __attribute__((ext_vector_type(16)));

__device__ __forceinline__ unsigned short f2bf_rne(float f) {
    unsigned u = __builtin_bit_cast(unsigned, f);
    unsigned r = (u + 0x7FFFu + ((u >> 16) & 1u)) >> 16;
    return (unsigned short)r;
}
__device__ __forceinline__ float bf2f(unsigned short b) {
    unsigned u = ((unsigned)b) << 16;
    return __builtin_bit_cast(float, u);
}
__device__ __forceinline__ unsigned cvt_pk_bf16(float a, float b) {
    unsigned r;
    asm("v_cvt_pk_bf16_f32 %0, %1, %2" : "=v"(r) : "v"(a), "v"(b));
    return r;   // [15:0]=bf16(a), [31:16]=bf16(b)
}
#define GLOAD_LDS16(gp, lp) \
    __builtin_amdgcn_global_load_lds((const __attribute__((address_space(1))) unsigned*)(gp), \
                                     (__attribute__((address_space(3))) unsigned*)(lp), 16, 0, 0)

// ---------------- degree histogram ----------------
__global__ void hist_kernel(const int* __restrict__ ei, int* __restrict__ cnt) {
    int e = blockIdx.x * blockDim.x + threadIdx.x;
    int stride = gridDim.x * blockDim.x;
    for (; e < N_EDGES; e += stride) {
        int d = ei[N_EDGES + e];
        if ((unsigned)d < N_NODES) atomicAdd(&cnt[d], 1);
    }
}

// ---------------- 3-phase scan ----------------
__global__ __launch_bounds__(256) void scan_sums(const int* __restrict__ cnt, int* __restrict__ bsum) {
    __shared__ int s[256];
    int t = threadIdx.x;
    int i = blockIdx.x * 256 + t;
    s[t] = (i < N_NODES) ? cnt[i] : 0;
    __syncthreads();
    #pragma unroll
    for (int off = 128; off > 0; off >>= 1) {
        if (t < off) s[t] += s[t + off];
        __syncthreads();
    }
    if (t == 0) bsum[blockIdx.x] = s[0];
}

__global__ __launch_bounds__(256) void scan_top(int* __restrict__ bsum) {
    __shared__ int s[256];
    int t = threadIdx.x;
    int v = (t < NBLK) ? bsum[t] : 0;
    s[t] = v;
    __syncthreads();
    for (int off = 1; off < 256; off <<= 1) {
        int x = (t >= off) ? s[t - off] : 0;
        __syncthreads();
        s[t] += x;
        __syncthreads();
    }
    if (t < NBLK) bsum[t] = s[t] - v;   // exclusive
}

__global__ __launch_bounds__(256) void scan_write(const int* __restrict__ cnt, const int* __restrict__ bsum,
                                                  int* __restrict__ rowoff, int* __restrict__ cursor,
                                                  float* __restrict__ dinv) {
    __shared__ int s[256];
    int t = threadIdx.x;
    int i = blockIdx.x * 256 + t;
    int v = (i < N_NODES) ? cnt[i] : 0;
    s[t] = v;
    __syncthreads();
    for (int off = 1; off < 256; off <<= 1) {
        int x = (t >= off) ? s[t - off] : 0;
        __syncthreads();
        s[t] += x;
        __syncthreads();
    }
    if (i < N_NODES) {
        int ro = bsum[blockIdx.x] + s[t] - v;   // exclusive
        rowoff[i] = ro;
        cursor[i] = ro;
        dinv[i]  = rsqrtf((float)v + 1.0f);
    }
}

// ---------------- W1 pack, SINGLE bf16 plane ----------------
// Wp[step 0..63][ci 0..7][lane 0..63][j 0..7] (bf16), 512KB total; k>=1000 zeroed.
__global__ __launch_bounds__(256) void wsplit_kernel(const float* __restrict__ W1,
                                                     unsigned short* __restrict__ Wp) {
    int idx = blockIdx.x * 256 + threadIdx.x;   // 256 cols * 1024 k
    int c = idx >> 10, k = idx & 1023;
    float v = (k < IN_DIM) ? W1[(size_t)k * HIDDEN + c] : 0.0f;
    int ci = c >> 5;
    int step = k >> 4, kk = k & 15;
    int lane = (kk >> 3) * 32 + (c & 31);
    int j = kk & 7;
    Wp[((size_t)(step * 8 + ci) * 64 + lane) * 8 + j] = f2bf_rne(v);
}

// ---------------- FUSED: gemm1 (blocks [0,GEMM_BLOCKS)) + scatter (rest) ----------------
// No data dependency between the two phases (both depend only on scan_write);
// disjoint resources: gemm1 = LDS+MFMA+L2-reads, scatter = HBM-writes+atomics.
__global__ __launch_bounds__(256, 4) void gemm_scatter_fused(const float* __restrict__ X,
                                                             const unsigned short* __restrict__ Wp,
                                                             const float* __restrict__ dinv,
                                                             unsigned short* __restrict__ G1b,
                                                             const int* __restrict__ ei,
                                                             int* __restrict__ cursor,
                                                             int* __restrict__ csr) {
    __shared__ unsigned short sA[2][1024];   // [mt 2][lane 64][8] bf16 = 2KB/buf
    __shared__ unsigned short sB[2][4096];   // [ci 8][lane 64][8]  bf16 = 8KB/buf
    const int tid = threadIdx.x;

    if (blockIdx.x >= GEMM_BLOCKS) {
        // ---- scatter path (grid-stride over edges) ----
        int e = (blockIdx.x - GEMM_BLOCKS) * 256 + tid;
        int stride = SCAT_BLOCKS * 256;
        for (; e < N_EDGES; e += stride) {
            int s = ei[e];
            int d = ei[N_EDGES + e];
            if ((unsigned)d < N_NODES && (unsigned)s < N_NODES) {
                int pos = atomicAdd(&cursor[d], 1);
                csr[pos] = s;
            }
        }
        return;
    }

    // ---- gemm1 path (identical to round-16 known-good) ----
    const int w   = tid >> 6;
    const int l   = tid & 63;
    const int lr  = l & 31;
    const int lq  = l >> 5;
    const int R   = w >> 1;
    const int C   = w & 1;
    const int m0  = blockIdx.x * 64;

    const int rl = tid >> 2;
    const int ss = tid & 3;
    const int smt   = rl >> 5;
    const int slane = (ss >> 1) * 32 + (rl & 31);
    const int sidx  = smt * 512 + slane * 8 + (ss & 1) * 4;   // shorts
    int rg = m0 + rl;
    const float* ap = X + (size_t)(rg < N_NODES ? rg : N_NODES - 1) * IN_DIM + ss * 4;
    const bool svalid_tail = (ss < 2);

    const unsigned short* bsrc = Wp + (size_t)(w * 2) * 512 + l * 8;

    f32x16 acc[4] = {};

    auto stageB = [&](int s, int buf) {
        const unsigned short* src = bsrc + (size_t)s * 4096;
        GLOAD_LDS16(src,       &sB[buf][(w * 2 + 0) * 512]);
        GLOAD_LDS16(src + 512, &sB[buf][(w * 2 + 1) * 512]);
    };
    auto cvtWriteA = [&](float4 f, int buf) {
        unsigned h0 = cvt_pk_bf16(f.x, f.y);
        unsigned h1 = cvt_pk_bf16(f.z, f.w);
        *(uint2*)&sA[buf][sidx] = make_uint2(h0, h1);
    };

    stageB(0, 0);
    cvtWriteA(*(const float4*)ap, 0);
    float4 rA = *(const float4*)(ap + 16);
    __syncthreads();

    #pragma unroll 1
    for (int s = 0; s < NSTEP; ++s) {
        const int buf = s & 1;
        if (s + 1 < NSTEP) stageB(s + 1, buf ^ 1);
        float4 rN = make_float4(0.f, 0.f, 0.f, 0.f);
        if (s + 2 < NSTEP && (s + 2 < NSTEP - 1 || svalid_tail))
            rN = *(const float4*)(ap + (size_t)(s + 2) * 16);
        if (s + 1 < NSTEP) cvtWriteA(rA, buf ^ 1);

        bf16x8 ah = *(const bf16x8*)&sA[buf][R * 512 + l * 8];
        bf16x8 b[4];
        #pragma unroll
        for (int ni = 0; ni < 4; ++ni)
            b[ni] = *(const bf16x8*)&sB[buf][(C * 4 + ni) * 512 + l * 8];
        #pragma unroll
        for (int ni = 0; ni < 4; ++ni)
            acc[ni] = __builtin_amdgcn_mfma_f32_32x32x16_bf16(ah, b[ni], acc[ni], 0, 0, 0);
        rA = rN;
        __syncthreads();
    }

    // epilogue -> slab-major: G1b[(slab*N + row)*32 + lr], slab = C*4+ni
    #pragma unroll
    for (int r = 0; r < 16; ++r) {
        int row = m0 + R * 32 + (r & 3) + 8 * (r >> 2) + 4 * lq;
        if (row >= N_NODES) continue;
        float dv = dinv[row];
        #pragma unroll
        for (int ni = 0; ni < 4; ++ni) {
            int slab = C * 4 + ni;
            G1b[((size_t)slab * N_NODES + row) * 32 + lr] = f2bf_rne(dv * acc[ni][r]);
        }
    }
}

// ---------------- slab-partitioned agg1 + partial gemm2 (slab-major g1b) ----------------
__global__ __launch_bounds__(256) void aggslab_kernel(const unsigned short* __restrict__ G,
                                                      const int* __restrict__ csr,
                                                      const int* __restrict__ rowoff,
                                                      const int* __restrict__ cnt,
                                                      const float* __restrict__ dinv,
                                                      const float* __restrict__ b1,
                                                      const float* __restrict__ W2,
                                                      float* __restrict__ part) {
    const int tid  = threadIdx.x;
    const int slab = blockIdx.x & 7;
    const int nb   = blockIdx.x >> 3;
    const int wave = tid >> 6, lane = tid & 63;
    const int g    = lane >> 3, sl = lane & 7;
    const int d    = nb * 32 + wave * 8 + g;
    if (d >= N_NODES) return;
    const unsigned short* Gs = G + (size_t)slab * N_NODES * 32;
    const int co = sl * 4;
    const int c0 = slab * 32 + co;

    ushort4 sv = *(const ushort4*)&Gs[(size_t)d * 32 + co];
    float ax = bf2f(sv.x), ay = bf2f(sv.y), az = bf2f(sv.z), aw = bf2f(sv.w);
    int beg = rowoff[d], num = cnt[d];
    int end = beg + num;
    int e = beg;
    for (; e + 8 <= end; e += 8) {
        int s0 = csr[e], s1 = csr[e+1], s2 = csr[e+2], s3 = csr[e+3];
        int s4 = csr[e+4], s5 = csr[e+5], s6 = csr[e+6], s7 = csr[e+7];
        ushort4 v0 = *(const ushort4*)&Gs[(size_t)s0 * 32 + co];
        ushort4 v1 = *(const ushort4*)&Gs[(size_t)s1 * 32 + co];
        ushort4 v2 = *(const ushort4*)&Gs[(size_t)s2 * 32 + co];
        ushort4 v3 = *(const ushort4*)&Gs[(size_t)s3 * 32 + co];
        ushort4 v4 = *(const ushort4*)&Gs[(size_t)s4 * 32 + co];
        ushort4 v5 = *(const ushort4*)&Gs[(size_t)s5 * 32 + co];
        ushort4 v6 = *(const ushort4*)&Gs[(size_t)s6 * 32 + co];
        ushort4 v7 = *(const ushort4*)&Gs[(size_t)s7 * 32 + co];
        ax += bf2f(v0.x); ay += bf2f(v0.y); az += bf2f(v0.z); aw += bf2f(v0.w);
        ax += bf2f(v1.x); ay += bf2f(v1.y); az += bf2f(v1.z); aw += bf2f(v1.w);
        ax += bf2f(v2.x); ay += bf2f(v2.y); az += bf2f(v2.z); aw += bf2f(v2.w);
        ax += bf2f(v3.x); ay += bf2f(v3.y); az += bf2f(v3.z); aw += bf2f(v3.w);
        ax += bf2f(v4.x); ay += bf2f(v4.y); az += bf2f(v4.z); aw += bf2f(v4.w);
        ax += bf2f(v5.x); ay += bf2f(v5.y); az += bf2f(v5.z); aw += bf2f(v5.w);
        ax += bf2f(v6.x); ay += bf2f(v6.y); az += bf2f(v6.z); aw += bf2f(v6.w);
        ax += bf2f(v7.x); ay += bf2f(v7.y); az += bf2f(v7.z); aw += bf2f(v7.w);
    }
    for (; e < end; ++e) {
        int s = csr[e];
        ushort4 v = *(const ushort4*)&Gs[(size_t)s * 32 + co];
        ax += bf2f(v.x); ay += bf2f(v.y); az += bf2f(v.z); aw += bf2f(v.w);
    }
    float dv = dinv[d];
    float4 bb = *(const float4*)&b1[c0];
    float zx = fmaxf(dv * ax + bb.x, 0.f);
    float zy = fmaxf(dv * ay + bb.y, 0.f);
    float zz = fmaxf(dv * az + bb.z, 0.f);
    float zw = fmaxf(dv * aw + bb.w, 0.f);
    float2 w0 = *(const float2*)&W2[(c0 + 0) * 2];
    float2 w1 = *(const float2*)&W2[(c0 + 1) * 2];
    float2 w2_ = *(const float2*)&W2[(c0 + 2) * 2];
    float2 w3 = *(const float2*)&W2[(c0 + 3) * 2];
    float p0 = zx * w0.x + zy * w1.x + zz * w2_.x + zw * w3.x;
    float p1 = zx * w0.y + zy * w1.y + zz * w2_.y + zw * w3.y;
    #pragma unroll
    for (int off = 1; off < 8; off <<= 1) {
        p0 += __shfl_xor(p0, off, 64);
        p1 += __shfl_xor(p1, off, 64);
    }
    if (sl == 0)
        *(float2*)&part[((size_t)slab * N_NODES + d) * 2] = make_float2(p0, p1);
}

// ---------------- g2 = dinv * sum_slab(part) ----------------
__global__ __launch_bounds__(256) void g2reduce_kernel(const float* __restrict__ part,
                                                       const float* __restrict__ dinv,
                                                       float* __restrict__ G2) {
    int i = blockIdx.x * 256 + threadIdx.x;
    if (i >= N_NODES) return;
    float a0 = 0.f, a1 = 0.f;
    #pragma unroll
    for (int s = 0; s < 8; ++s) {
        float2 p = *(const float2*)&part[((size_t)s * N_NODES + i) * 2];
        a0 += p.x; a1 += p.y;
    }
    float dv = dinv[i];
    G2[i * 2 + 0] = dv * a0;
    G2[i * 2 + 1] = dv * a1;
}

// ---------------- agg2 ----------------
__global__ __launch_bounds__(256) void agg2_kernel(const float* __restrict__ G2,
                                                   const int* __restrict__ csr,
                                                   const int* __restrict__ rowoff,
                                                   const int* __restrict__ cnt,
                                                   const float* __restrict__ dinv,
                                                   const float* __restrict__ b2,
                                                   float* __restrict__ out) {
    int wave = threadIdx.x >> 6, lane = threadIdx.x & 63;
    int d = blockIdx.x * 4 + wave;
    if (d >= N_NODES) return;
    int beg = rowoff[d], num = cnt[d];
    float a0 = 0.f, a1 = 0.f;
    for (int e = lane; e < num; e += 64) {
        int s = csr[beg + e];
        float2 g = *(const float2*)&G2[s * 2];
        a0 += g.x; a1 += g.y;
    }
    #pragma unroll
    for (int off = 32; off; off >>= 1) {
        a0 += __shfl_xor(a0, off, 64);
        a1 += __shfl_xor(a1, off, 64);
    }
    if (lane == 0) {
        float2 self = *(const float2*)&G2[d * 2];
        float dv = dinv[d];
        out[d * 2 + 0] = dv * (a0 + self.x) + b2[0];
        out[d * 2 + 1] = dv * (a1 + self.y) + b2[1];
    }
}

// ---------------- workspace layout (bytes) ----------------
#define OFF_CNT     0u
#define OFF_ROWOFF  262144u
#define OFF_CURSOR  524288u
#define OFF_DINV    786432u
#define OFF_BSUM    1048576u
#define OFF_CSR     1310720u
#define OFF_WP      8388608u     // 512 KB packed single-plane
#define OFF_G1B     9437184u     // 25.6 MB slab-major
#define OFF_G2      35651584u    // 400 KB
#define OFF_PART    36700160u    // 3.2 MB
// total ~40 MB

extern "C" void kernel_launch(void* const* d_in, const int* in_sizes, int n_in,
                              void* d_out, int out_size, void* d_ws, size_t ws_size,
                              hipStream_t stream) {
    const float* x  = (const float*)d_in[0];
    const float* W1 = (const float*)d_in[1];
    const float* b1 = (const float*)d_in[2];
    const float* W2 = (const float*)d_in[3];
    const float* b2 = (const float*)d_in[4];
    const int*   ei = (const int*)d_in[5];

    char* ws = (char*)d_ws;
    int*   cnt    = (int*)  (ws + OFF_CNT);
    int*   rowoff = (int*)  (ws + OFF_ROWOFF);
    int*   cursor = (int*)  (ws + OFF_CURSOR);
    float* dinv   = (float*)(ws + OFF_DINV);
    int*   bsum   = (int*)  (ws + OFF_BSUM);
    int*   csr    = (int*)  (ws + OFF_CSR);
    unsigned short* wp  = (unsigned short*)(ws + OFF_WP);
    unsigned short* g1b = (unsigned short*)(ws + OFF_G1B);
    float* g2     = (float*)(ws + OFF_G2);
    float* part   = (float*)(ws + OFF_PART);
    float* out    = (float*)d_out;

    hipMemsetAsync(cnt, 0, N_NODES * sizeof(int), stream);
    wsplit_kernel<<<1024, 256, 0, stream>>>(W1, wp);
    hist_kernel<<<2048, 256, 0, stream>>>(ei, cnt);
    scan_sums<<<NBLK, 256, 0, stream>>>(cnt, bsum);
    scan_top<<<1, 256, 0, stream>>>(bsum);
    scan_write<<<NBLK, 256, 0, stream>>>(cnt, bsum, rowoff, cursor, dinv);

    gemm_scatter_fused<<<GEMM_BLOCKS + SCAT_BLOCKS, 256, 0, stream>>>(x, wp, dinv, g1b,
                                                                      ei, cursor, csr);

    aggslab_kernel<<<8 * ((N_NODES + 31) / 32), 256, 0, stream>>>(g1b, csr, rowoff, cnt, dinv, b1, W2, part);
    g2reduce_kernel<<<NBLK, 256, 0, stream>>>(part, dinv, g2);
    agg2_kernel<<<(N_NODES + 3) / 4, 256, 0, stream>>>(g2, csr, rowoff, cnt, dinv, b2, out);
}